// Round 1
// baseline (810.529 us; speedup 1.0000x reference)
//
#include <hip/hip_runtime.h>
#include <math.h>

// Problem constants
#define D_TOT 320
#define D_ZL  64
#define D_XO  256
#define NH    16
#define NB_B  1024
#define NEG   0.01f
#define HALF_LOG2PI 0.9189385332046727f

// Workspace layout (float offsets)
#define W0P_OFF  0
#define W0P_SZ   (5*320*64*16)          // 1,638,400
#define W1P_OFF  (W0P_OFF + W0P_SZ)
#define W1P_SZ   (5*256*64)             // 81,920
#define W2P_OFF  (W1P_OFF + W1P_SZ)
#define W2P_SZ   (5*16*64)              // 5,120
#define CM_OFF   (W2P_OFF + W2P_SZ)
#define CM_SZ    (320*320)              // 102,400
#define PART_OFF (CM_OFF + CM_SZ)
#define PART_SZ  1024
#define PRE_TOTAL (CM_SZ + W1P_SZ + W2P_SZ + D_TOT + PART_SZ)  // 190,784

// Precompute: cmask = fm ? exp(-mask_param) : INF  (folds fixed mask: adj==0),
// repack W1/W2 for coalesced lane-major reads, write std to out, zero partials.
__global__ __launch_bounds__(256) void pre_small(
    const float* __restrict__ mp, const float* __restrict__ W1,
    const float* __restrict__ W2, const float* __restrict__ logvar,
    float* __restrict__ ws, float* __restrict__ out) {
  int i = blockIdx.x * 256 + threadIdx.x;
  if (i < CM_SZ) {
    int j = i / 320, k = i - j * 320;
    bool fm = (k < D_ZL) ? (j == k) : (j != k);
    ws[CM_OFF + i] = fm ? expf(-mp[i]) : INFINITY;
  }
  int i1 = i - CM_SZ;
  if (i1 >= 0 && i1 < W1P_SZ) {
    int lane = i1 & 63; int r = i1 >> 6;       // r = tile*256 + hg
    int tile = r >> 8;  int hg = r & 255;
    ws[W1P_OFF + i1] = W1[(tile * 64 + lane) * 256 + hg];
  }
  int i2 = i1 - W1P_SZ;
  if (i2 >= 0 && i2 < W2P_SZ) {
    int lane = i2 & 63; int r = i2 >> 6;       // r = tile*16 + h
    int tile = r >> 4;  int h = r & 15;
    ws[W2P_OFF + i2] = W2[(tile * 64 + lane) * 16 + h];
  }
  int i3 = i2 - W2P_SZ;
  if (i3 >= 0 && i3 < D_TOT) {
    out[1 + NB_B * D_TOT + i3] = expf(0.5f * logvar[i3]);
  }
  int i4 = i3 - D_TOT;
  if (i4 >= 0 && i4 < PART_SZ) ws[PART_OFF + i4] = 0.0f;
}

// Repack W0[k][j][h] -> W0p[tile][j][lane][h]  (k = tile*64+lane)
__global__ __launch_bounds__(256) void repack_w0(
    const float* __restrict__ W0, float* __restrict__ ws) {
  int i = blockIdx.x * 256 + threadIdx.x;      // < 1,638,400
  int h = i & 15;    int r = i >> 4;           // r = (tile*320+j)*64 + lane
  int lane = r & 63; int jj = r >> 6;          // jj = tile*320 + j
  int tile = jj / 320; int j = jj - tile * 320;
  ws[W0P_OFF + i] = W0[((tile * 64 + lane) * 320 + j) * 16 + h];
}

// Main fused kernel: adj -> masked -> MLP -> mu, logp partial sums.
// Grid: 640 blocks of 256 (4 waves). Each block: one k-tile (64 k's) x 8 batch rows.
// Each wave: 2 batch rows; lane <-> k (coalesced u reads).
__global__ __launch_bounds__(256) void main_k(
    const float* __restrict__ x, const float* __restrict__ z,
    const float* __restrict__ u, const float* __restrict__ bias0,
    const float* __restrict__ bias1, const float* __restrict__ bias2,
    const float* __restrict__ logvar, float* __restrict__ ws,
    float* __restrict__ out) {
  // XCD swizzle: group same-k-tile blocks per XCD (W0p slice stays in 4MB L2)
  int swz  = (blockIdx.x & 7) * 80 + (blockIdx.x >> 3);  // bijective, 640=8*80
  int tile = swz >> 7;        // / 128  -> [0,5)
  int bblk = swz & 127;
  int tid  = threadIdx.x;
  int wave = tid >> 6, lane = tid & 63;
  int k     = tile * 64 + lane;
  int bbase = bblk * 8;
  int bA    = bbase + wave * 2;
  int bB    = bA + 1;

  __shared__ float av[8][320];
  for (int t = tid; t < 8 * 320; t += 256) {
    int bb = t / 320, jj = t - (t / 320) * 320;
    av[bb][jj] = (jj < D_ZL) ? z[(bbase + bb) * D_ZL + jj]
                             : x[(bbase + bb) * D_XO + (jj - D_ZL)];
  }
  __syncthreads();

  float acc0[16], acc1[16];
#pragma unroll
  for (int h = 0; h < NH; ++h) {
    float bv = bias0[k * NH + h];
    acc0[h] = bv; acc1[h] = bv;
  }

  const float* w0p = ws + W0P_OFF + tile * (320 * 64 * 16) + lane * 16;
  const float* cmp = ws + CM_OFF + k;
  const float* uA  = u + bA * (320 * 320) + k;
  const float* uB  = u + bB * (320 * 320) + k;
  const float* avA = &av[wave * 2][0];
  const float* avB = &av[wave * 2 + 1][0];

#pragma unroll 2
  for (int j = 0; j < 320; ++j) {
    float c  = cmp[j * 320];
    float u0 = uA[j * 320];
    float u1 = uB[j * 320];
    // sigmoid(m + log(u/(1-u))) = u / (u + e^{-m} (1-u));  c==INF -> 0 (masked)
    float r0 = __builtin_amdgcn_rcpf(fmaf(c, 1.0f - u0, u0));
    float r1 = __builtin_amdgcn_rcpf(fmaf(c, 1.0f - u1, u1));
    float m0 = u0 * r0 * avA[j];
    float m1 = u1 * r1 * avB[j];
    const float4* wr = (const float4*)(w0p + j * 1024);
    float4 wv0 = wr[0], wv1 = wr[1], wv2 = wr[2], wv3 = wr[3];
    acc0[ 0]=fmaf(m0,wv0.x,acc0[ 0]); acc0[ 1]=fmaf(m0,wv0.y,acc0[ 1]);
    acc0[ 2]=fmaf(m0,wv0.z,acc0[ 2]); acc0[ 3]=fmaf(m0,wv0.w,acc0[ 3]);
    acc0[ 4]=fmaf(m0,wv1.x,acc0[ 4]); acc0[ 5]=fmaf(m0,wv1.y,acc0[ 5]);
    acc0[ 6]=fmaf(m0,wv1.z,acc0[ 6]); acc0[ 7]=fmaf(m0,wv1.w,acc0[ 7]);
    acc0[ 8]=fmaf(m0,wv2.x,acc0[ 8]); acc0[ 9]=fmaf(m0,wv2.y,acc0[ 9]);
    acc0[10]=fmaf(m0,wv2.z,acc0[10]); acc0[11]=fmaf(m0,wv2.w,acc0[11]);
    acc0[12]=fmaf(m0,wv3.x,acc0[12]); acc0[13]=fmaf(m0,wv3.y,acc0[13]);
    acc0[14]=fmaf(m0,wv3.z,acc0[14]); acc0[15]=fmaf(m0,wv3.w,acc0[15]);
    acc1[ 0]=fmaf(m1,wv0.x,acc1[ 0]); acc1[ 1]=fmaf(m1,wv0.y,acc1[ 1]);
    acc1[ 2]=fmaf(m1,wv0.z,acc1[ 2]); acc1[ 3]=fmaf(m1,wv0.w,acc1[ 3]);
    acc1[ 4]=fmaf(m1,wv1.x,acc1[ 4]); acc1[ 5]=fmaf(m1,wv1.y,acc1[ 5]);
    acc1[ 6]=fmaf(m1,wv1.z,acc1[ 6]); acc1[ 7]=fmaf(m1,wv1.w,acc1[ 7]);
    acc1[ 8]=fmaf(m1,wv2.x,acc1[ 8]); acc1[ 9]=fmaf(m1,wv2.y,acc1[ 9]);
    acc1[10]=fmaf(m1,wv2.z,acc1[10]); acc1[11]=fmaf(m1,wv2.w,acc1[11]);
    acc1[12]=fmaf(m1,wv3.x,acc1[12]); acc1[13]=fmaf(m1,wv3.y,acc1[13]);
    acc1[14]=fmaf(m1,wv3.z,acc1[14]); acc1[15]=fmaf(m1,wv3.w,acc1[15]);
  }

  // Layer 1: h1[g] = b1[k][g] + sum_h leaky(h0[h]) * W1[k][h][g]
  const float* w1p = ws + W1P_OFF + tile * (256 * 64) + lane;
  const float* w2p = ws + W2P_OFF + tile * (16 * 64) + lane;
  float h1a[16], h1b[16];
#pragma unroll
  for (int g = 0; g < NH; ++g) {
    float bv = bias1[k * NH + g];
    h1a[g] = bv; h1b[g] = bv;
  }
#pragma unroll
  for (int h = 0; h < NH; ++h) {
    float v0 = acc0[h]; v0 = v0 > 0.0f ? v0 : NEG * v0;
    float v1 = acc1[h]; v1 = v1 > 0.0f ? v1 : NEG * v1;
#pragma unroll
    for (int g = 0; g < NH; ++g) {
      float wv = w1p[(h * 16 + g) * 64];
      h1a[g] = fmaf(v0, wv, h1a[g]);
      h1b[g] = fmaf(v1, wv, h1b[g]);
    }
  }
  // Layer 2: mu = b2[k] + sum_h leaky(h1[h]) * W2[k][h]
  float muA = bias2[k], muB = bias2[k];
#pragma unroll
  for (int h = 0; h < NH; ++h) {
    float v0 = h1a[h]; v0 = v0 > 0.0f ? v0 : NEG * v0;
    float v1 = h1b[h]; v1 = v1 > 0.0f ? v1 : NEG * v1;
    float wv = w2p[h * 64];
    muA = fmaf(v0, wv, muA);
    muB = fmaf(v1, wv, muB);
  }
  out[1 + bA * 320 + k] = muA;
  out[1 + bB * 320 + k] = muB;

  // log-prob: logp = -0.5*diff^2 - 0.5*logvar - 0.5*log(2pi);  log(std)=0.5*logvar
  float lv   = logvar[k];
  float rstd = expf(-0.5f * lv);
  float dA = (avA[k] - muA) * rstd;
  float dB = (avB[k] - muB) * rstd;
  float base = -0.5f * lv - HALF_LOG2PI;
  float lpA = fmaf(-0.5f * dA, dA, base);
  float lpB = fmaf(-0.5f * dB, dB, base);
#pragma unroll
  for (int off = 32; off > 0; off >>= 1) {
    lpA += __shfl_xor(lpA, off);
    lpB += __shfl_xor(lpB, off);
  }
  if (lane == 0) {
    atomicAdd(&ws[PART_OFF + bA], lpA);
    atomicAdd(&ws[PART_OFF + bB], lpB);
  }
}

// Deterministic final reduce: recons = mean_b(partial[b])
__global__ __launch_bounds__(256) void finalize(
    const float* __restrict__ ws, float* __restrict__ out) {
  int tid = threadIdx.x;
  float v = 0.0f;
  for (int i = tid; i < PART_SZ; i += 256) v += ws[PART_OFF + i];
#pragma unroll
  for (int off = 32; off > 0; off >>= 1) v += __shfl_xor(v, off);
  __shared__ float s[4];
  if ((tid & 63) == 0) s[tid >> 6] = v;
  __syncthreads();
  if (tid == 0) out[0] = (s[0] + s[1] + s[2] + s[3]) * (1.0f / (float)NB_B);
}

extern "C" void kernel_launch(void* const* d_in, const int* in_sizes, int n_in,
                              void* d_out, int out_size, void* d_ws, size_t ws_size,
                              hipStream_t stream) {
  const float* x  = (const float*)d_in[0];
  const float* z  = (const float*)d_in[1];
  const float* u  = (const float*)d_in[2];
  const float* mp = (const float*)d_in[3];
  const float* W0 = (const float*)d_in[4];
  const float* b0 = (const float*)d_in[5];
  const float* W1 = (const float*)d_in[6];
  const float* b1 = (const float*)d_in[7];
  const float* W2 = (const float*)d_in[8];
  const float* b2 = (const float*)d_in[9];
  const float* lv = (const float*)d_in[10];
  float* out = (float*)d_out;
  float* ws  = (float*)d_ws;

  hipLaunchKernelGGL(pre_small, dim3((PRE_TOTAL + 255) / 256), dim3(256), 0, stream,
                     mp, W1, W2, lv, ws, out);
  hipLaunchKernelGGL(repack_w0, dim3(W0P_SZ / 256), dim3(256), 0, stream, W0, ws);
  hipLaunchKernelGGL(main_k, dim3(640), dim3(256), 0, stream,
                     x, z, u, b0, b1, b2, lv, ws, out);
  hipLaunchKernelGGL(finalize, dim3(1), dim3(256), 0, stream, ws, out);
}